// Round 12
// baseline (152.507 us; speedup 1.0000x reference)
//
#include <hip/hip_runtime.h>

#define B_DIM 4
#define C_DIM 256
#define N_DIM 4096
#define CT_DIM 256
#define SPLIT 4
#define KVBLK 32

typedef float f32x4 __attribute__((ext_vector_type(4)));
typedef float f32x16 __attribute__((ext_vector_type(16)));
typedef short bf16x8 __attribute__((ext_vector_type(8)));
typedef short bf16x4 __attribute__((ext_vector_type(4)));
typedef unsigned int u32;

static __device__ __forceinline__ short f2bf(float f) {
  u32 u = __builtin_bit_cast(u32, f);
  u += 0x7fffu + ((u >> 16) & 1u);
  return (short)(u >> 16);
}
static __device__ __forceinline__ float bf2f(short s) {
  u32 u = ((u32)(unsigned short)s) << 16;
  return __builtin_bit_cast(float, u);
}
// v_cvt_pk_bf16_f32: packs 2 f32 -> 2 bf16 (RNE) in one VALU op.
static __device__ __forceinline__ u32 cvtpk(float lo, float hi) {
  u32 w;
  asm("v_cvt_pk_bf16_f32 %0, %1, %2" : "=v"(w) : "v"(lo), "v"(hi));
  return w;
}

#define MFMA(a, b, c) __builtin_amdgcn_mfma_f32_16x16x32_bf16((a), (b), (c), 0, 0, 0)
#define MFMA32(a, b, c) __builtin_amdgcn_mfma_f32_32x32x16_bf16((a), (b), (c), 0, 0, 0)

static __device__ __forceinline__ void gload16(const void* g, void* l) {
  __builtin_amdgcn_global_load_lds(
      (const __attribute__((address_space(1))) u32*)(g),
      (__attribute__((address_space(3))) u32*)(l), 16, 0, 0);
}

#define LDS_STRIDE 272
// q pre-scale: (1/16) * log2(e) so softmax runs in exp2 basis
#define QSCALE 0.09016844005556021f
// defer-rescale threshold (exp2 basis): P bounded by 2^8
#define THR 8.0f

// Kernel 0: one-shot weight conversion to bf16 (Wq pre-scaled by QSCALE).
__global__ __launch_bounds__(256) void wconv_kernel(
    const float* __restrict__ Wq, const float* __restrict__ Wk,
    const float* __restrict__ Wv, const float* __restrict__ Wo,
    short* __restrict__ wqb, short* __restrict__ wkb,
    short* __restrict__ wvb, short* __restrict__ wob) {
  const int t = blockIdx.x * 256 + threadIdx.x;  // 0..81919
  const float* src;
  short* dst;
  int off;
  float sc = 1.0f;
  if (t < 16384)      { src = Wq; dst = wqb; off = t;         sc = QSCALE; }
  else if (t < 32768) { src = Wk; dst = wkb; off = t - 16384; }
  else if (t < 49152) { src = Wv; dst = wvb; off = t - 32768; }
  else                { src = Wo; dst = wob; off = t - 49152; }
  f32x4 v = *reinterpret_cast<const f32x4*>(src + (size_t)off * 4);
  struct W2 { u32 a, b; } wv2;
  wv2.a = cvtpk(v[0] * sc, v[1] * sc);
  wv2.b = cvtpk(v[2] * sc, v[3] * sc);
  *reinterpret_cast<bf16x4*>(dst + (size_t)off * 4) = __builtin_bit_cast(bf16x4, wv2);
}

// Kernel 1: projections. grid = B * (N/32) = 512, block = 256 (2 blocks/CU).
// Wave w owns ct range [w*64, w*64+64); block handles 32 n rows.
// qb[b][n][ct] (q pre-scaled via wqb);
// kb[b][n][ct ^ ((n&15)<<3)];
// vtb[b][ct][(n&~31) + ((n&31) ^ (((ct>>1)&3)<<3))];
// xT[b][n][c] plain.
__global__ __launch_bounds__(256) void proj_kernel(
    const float* __restrict__ x, const short* __restrict__ wqb,
    const short* __restrict__ wkb, const short* __restrict__ wvb,
    short* __restrict__ qb, short* __restrict__ kb,
    short* __restrict__ vtb, short* __restrict__ xT) {
  __shared__ short xt[32 * LDS_STRIDE];
  const int b = blockIdx.x >> 7;
  const int n0 = (blockIdx.x & 127) * 32;
  const int tid = threadIdx.x;
  const int w = tid >> 6;
  const int l = tid & 63;
  const int lr = l & 15;
  const int lg = l >> 4;

  // stage x tile (C=256 x 32 n) into LDS transposed as bf16, cvtpk pairs
  {
    const float* xb = x + (size_t)b * C_DIM * N_DIM + n0;
    const int n = tid & 31;
    const int cp = (tid >> 5) * 2;   // 0,2,..,14
#pragma unroll 4
    for (int it = 0; it < 16; ++it) {
      const int c = it * 16 + cp;
      const float v0 = xb[(size_t)c * N_DIM + n];
      const float v1 = xb[(size_t)(c + 1) * N_DIM + n];
      *reinterpret_cast<u32*>(&xt[n * LDS_STRIDE + c]) = cvtpk(v0, v1);
    }
  }
  __syncthreads();

  // write xT to global (coalesced, from LDS)
  {
    const int nn = tid >> 5;         // 0..7
    const int cc = (tid & 31) * 8;
#pragma unroll
    for (int it = 0; it < 4; ++it) {
      const int row = it * 8 + nn;
      bf16x8 v = *reinterpret_cast<const bf16x8*>(&xt[row * LDS_STRIDE + cc]);
      *reinterpret_cast<bf16x8*>(&xT[((size_t)(b * N_DIM) + n0 + row) * C_DIM + cc]) = v;
    }
  }

  f32x4 zz; zz[0] = 0.f; zz[1] = 0.f; zz[2] = 0.f; zz[3] = 0.f;

  // q and k passes: output (n, ct). wave w owns ct range [w*64, w*64+64)
  for (int pass = 0; pass < 2; ++pass) {
    const short* W = pass ? wkb : wqb;
    short* dst = pass ? kb : qb;
    f32x4 acc[4][2];
#pragma unroll
    for (int cs = 0; cs < 4; ++cs)
#pragma unroll
      for (int ns = 0; ns < 2; ++ns) acc[cs][ns] = zz;
#pragma unroll
    for (int kk = 0; kk < 8; ++kk) {
      bf16x8 af[2], bf[4];
#pragma unroll
      for (int ns = 0; ns < 2; ++ns)
        af[ns] = *reinterpret_cast<const bf16x8*>(&xt[(ns * 16 + lr) * LDS_STRIDE + kk * 32 + lg * 8]);
#pragma unroll
      for (int cs = 0; cs < 4; ++cs)
        bf[cs] = *reinterpret_cast<const bf16x8*>(
            &W[(size_t)(w * 64 + cs * 16 + lr) * C_DIM + kk * 32 + lg * 8]);
#pragma unroll
      for (int cs = 0; cs < 4; ++cs)
#pragma unroll
        for (int ns = 0; ns < 2; ++ns) acc[cs][ns] = MFMA(af[ns], bf[cs], acc[cs][ns]);
    }
#pragma unroll
    for (int cs = 0; cs < 4; ++cs)
#pragma unroll
      for (int ns = 0; ns < 2; ++ns)
#pragma unroll
        for (int r = 0; r < 4; ++r) {
          const int n = n0 + ns * 16 + lg * 4 + r;
          const int ct = w * 64 + cs * 16 + lr;
          const int sw = pass ? ((lg * 4 + r) << 3) : 0;  // n&15 == lg*4+r
          dst[((size_t)(b * N_DIM) + n) * CT_DIM + (ct ^ sw)] = f2bf(acc[cs][ns][r]);
        }
  }

  // v pass: output (ct, n), swizzled within 32-wide n groups (f = (ct>>1)&3)
  {
    f32x4 acc[4][2];
#pragma unroll
    for (int as = 0; as < 4; ++as)
#pragma unroll
      for (int ns = 0; ns < 2; ++ns) acc[as][ns] = zz;
#pragma unroll
    for (int kk = 0; kk < 8; ++kk) {
      bf16x8 af[4], bf[2];
#pragma unroll
      for (int as = 0; as < 4; ++as)
        af[as] = *reinterpret_cast<const bf16x8*>(
            &wvb[(size_t)(w * 64 + as * 16 + lr) * C_DIM + kk * 32 + lg * 8]);
#pragma unroll
      for (int ns = 0; ns < 2; ++ns)
        bf[ns] = *reinterpret_cast<const bf16x8*>(&xt[(ns * 16 + lr) * LDS_STRIDE + kk * 32 + lg * 8]);
#pragma unroll
      for (int as = 0; as < 4; ++as)
#pragma unroll
        for (int ns = 0; ns < 2; ++ns) acc[as][ns] = MFMA(af[as], bf[ns], acc[as][ns]);
    }
#pragma unroll
    for (int as = 0; as < 4; ++as)
#pragma unroll
      for (int ns = 0; ns < 2; ++ns)
#pragma unroll
        for (int r = 0; r < 4; ++r) {
          const int ct = w * 64 + as * 16 + lg * 4 + r;
          const int nl = ns * 16 + lr;                 // 0..31
          const int nsw = nl ^ (((ct >> 1) & 3) << 3); // n&31 swizzle, n0 32-aligned
          vtb[((size_t)(b * CT_DIM) + ct) * N_DIM + n0 + nsw] = f2bf(acc[as][ns][r]);
        }
  }
}

// Kernel 2: flash attention, swapped-QK 32x32x16, O^T accumulation (verified
// structure) + defer-rescale THR=8. grid = 256 (XCD-pinned), block = 512.
__global__ __launch_bounds__(512, 1) void attn_kernel(
    const short* __restrict__ qb, const short* __restrict__ kb,
    const short* __restrict__ vtb, short* __restrict__ Opart,
    float* __restrict__ mpart, float* __restrict__ lpart) {
  __shared__ short klds[3][KVBLK * 256];   // 3 x 16 KB
  __shared__ short vlds[3][256 * KVBLK];   // 3 x 16 KB

  const int bid = blockIdx.x;
  const int xcd = bid & 7;
  const int idx = bid >> 3;          // 0..31
  const int qt = idx & 15;
  const int bs = (idx >> 4) * 8 + xcd;  // 0..15
  const int b = bs >> 2;
  const int s = bs & 3;

  const int tid = threadIdx.x;
  const int w = tid >> 6;            // 0..7
  const int l = tid & 63;
  const int q5 = l & 31;             // this lane's q-row (within wave tile)
  const int h = l >> 5;              // half-wave
  const int nbase = qt * 256 + w * 32;

  const char* kgbase = (const char*)(kb + ((size_t)b * N_DIM) * CT_DIM);
  const char* vgbase = (const char*)(vtb + ((size_t)b * CT_DIM) * N_DIM);
  const int m_begin = s * (N_DIM / SPLIT);
  const int NT = (N_DIM / SPLIT) / KVBLK;  // 32

  // Q as B-operand fragments: lane needs Q[qrow][kk*16 + h*8 + 0..7]
  bf16x8 qf[16];
  {
    const short* qrow = qb + ((size_t)(b * N_DIM) + nbase + q5) * CT_DIM + h * 8;
#pragma unroll
    for (int kk = 0; kk < 16; ++kk)
      qf[kk] = *reinterpret_cast<const bf16x8*>(qrow + kk * 16);
  }

  f32x16 z16;
#pragma unroll
  for (int r = 0; r < 16; ++r) z16[r] = 0.f;
  f32x16 o8[8];  // O^T[ct = g*32 + crow(reg,h)][q = q5]
#pragma unroll
  for (int g = 0; g < 8; ++g) o8[g] = z16;
  float m_r = -1e30f, l_r = 0.f;   // in exp2 basis

  const int ksw = (q5 & 15) << 3;
  const int vswz = ((q5 >> 1) & 3) << 3;

  auto stage = [&](int m0, int buf) {
    const char* ks = kgbase + (size_t)m0 * 512;  // 32 rows x 512B contiguous
#pragma unroll
    for (int i = 0; i < 2; ++i)
      gload16(ks + (w * 2 + i) * 1024 + l * 16,
              (char*)klds[buf] + (w * 2 + i) * 1024);
#pragma unroll
    for (int i = 0; i < 2; ++i) {
      const int base_ct = (w * 2 + i) * 16;
      gload16(vgbase + ((size_t)(base_ct + (l >> 2)) * N_DIM + m0) * 2 + (l & 3) * 16,
              (char*)vlds[buf] + base_ct * 64);
    }
  };

  auto compute = [&](int cur) {
    // ---- S^T = K Q : lane holds S[q5][key = crow(reg,h)] ----
    f32x16 sacc = z16;
    __builtin_amdgcn_s_setprio(1);
#pragma unroll
    for (int kk = 0; kk < 16; ++kk) {
      bf16x8 kf = *reinterpret_cast<const bf16x8*>(
          &klds[cur][q5 * 256 + ((kk * 16 + h * 8) ^ ksw)]);
      sacc = MFMA32(kf, qf[kk], sacc);
    }
    __builtin_amdgcn_s_setprio(0);

    // ---- in-lane softmax (exp2 basis), deferred rescale (THR=8) ----
    float t0 = fmaxf(fmaxf(fmaxf(sacc[0], sacc[1]), fmaxf(sacc[2], sacc[3])),
                     fmaxf(fmaxf(sacc[4], sacc[5]), fmaxf(sacc[6], sacc[7])));
    float t1 = fmaxf(fmaxf(fmaxf(sacc[8], sacc[9]), fmaxf(sacc[10], sacc[11])),
                     fmaxf(fmaxf(sacc[12], sacc[13]), fmaxf(sacc[14], sacc[15])));
    float pmax = fmaxf(t0, t1);
    pmax = fmaxf(pmax, __shfl_xor(pmax, 32));

    const bool need = (bool)__any(pmax - m_r > THR);
    if (need) {
      const float mnew = fmaxf(m_r, pmax);
      const float corr = __builtin_exp2f(m_r - mnew);
      m_r = mnew;
      l_r *= corr;
#pragma unroll
      for (int g = 0; g < 8; ++g)
#pragma unroll
        for (int r = 0; r < 16; ++r) o8[g][r] *= corr;
    }
    float rsum = 0.f;
#pragma unroll
    for (int r = 0; r < 16; ++r) {
      const float p = __builtin_exp2f(sacc[r] - m_r);
      sacc[r] = p;
      rsum += p;
    }
    rsum += __shfl_xor(rsum, 32);
    l_r += rsum;

    // ---- P^T B-operand fragments (cvt_pk + one shfl pair per step) ----
    bf16x8 pb[2];
#pragma unroll
    for (int step = 0; step < 2; ++step) {
      const u32 pA0 = cvtpk(sacc[8 * step + 0], sacc[8 * step + 1]);
      const u32 pA1 = cvtpk(sacc[8 * step + 2], sacc[8 * step + 3]);
      const u32 pB0 = cvtpk(sacc[8 * step + 4], sacc[8 * step + 5]);
      const u32 pB1 = cvtpk(sacc[8 * step + 6], sacc[8 * step + 7]);
      const u32 loc0 = h ? pB0 : pA0;
      const u32 loc1 = h ? pB1 : pA1;
      const u32 rem0 = h ? pA0 : pB0;
      const u32 rem1 = h ? pA1 : pB1;
      const u32 g0 = __shfl_xor(rem0, 32);
      const u32 g1 = __shfl_xor(rem1, 32);
      struct W4 { u32 a, b, c, d; };
      W4 wv;
      wv.a = h ? g0 : loc0;
      wv.b = h ? g1 : loc1;
      wv.c = h ? loc0 : g0;
      wv.d = h ? loc1 : g1;
      pb[step] = __builtin_bit_cast(bf16x8, wv);
    }

    // ---- O^T += V^T P^T ----
    __builtin_amdgcn_s_setprio(1);
#pragma unroll
    for (int step = 0; step < 2; ++step) {
#pragma unroll
      for (int g = 0; g < 8; ++g) {
        const int ct = g * 32 + q5;
        bf16x8 vf = *reinterpret_cast<const bf16x8*>(
            &vlds[cur][ct * KVBLK + ((step * 16 + h * 8) ^ vswz)]);
        o8[g] = MFMA32(vf, pb[step], o8[g]);
      }
    }
    __builtin_amdgcn_s_setprio(0);
  };

  // ---- main loop: 1 barrier per iter, triple buffer, distance-1 prefetch ----
  stage(m_begin, 0);
  int cur = 0;
#pragma unroll 1
  for (int t = 0; t < NT; ++t) {
    if (t + 1 < NT) {
      stage(m_begin + (t + 1) * KVBLK, cur == 2 ? 0 : cur + 1);
      asm volatile("s_waitcnt vmcnt(4)" ::: "memory");
    } else {
      asm volatile("s_waitcnt vmcnt(0)" ::: "memory");
    }
    __builtin_amdgcn_s_barrier();
    __builtin_amdgcn_sched_barrier(0);
    compute(cur);
    cur = (cur == 2) ? 0 : cur + 1;
  }

  // ---- write partials: Opart[s][b][n][ct] bf16, bf16x4 packed per (g,rq) ----
  short* ob = Opart + (size_t)(s * B_DIM + b) * N_DIM * CT_DIM;
  const int n = nbase + q5;
#pragma unroll
  for (int g = 0; g < 8; ++g)
#pragma unroll
    for (int rq = 0; rq < 4; ++rq) {
      struct W2 { u32 a, b; };
      W2 wv;
      wv.a = cvtpk(o8[g][rq * 4 + 0], o8[g][rq * 4 + 1]);
      wv.b = cvtpk(o8[g][rq * 4 + 2], o8[g][rq * 4 + 3]);
      *reinterpret_cast<bf16x4*>(&ob[(size_t)n * CT_DIM + g * 32 + rq * 8 + h * 4]) =
          __builtin_bit_cast(bf16x4, wv);
    }
  if (l < 32) {
    mpart[(size_t)(s * B_DIM + b) * N_DIM + n] = m_r;
    lpart[(size_t)(s * B_DIM + b) * N_DIM + n] = l_r;
  }
}

// Kernel 3: combine SPLIT partials -> ctxT bf16 (B, N, CT).
// grid = B*N/8 blocks x 256; thread = (one n-row) x (8 ct). Vectorized bf16x8.
__global__ __launch_bounds__(256) void combine_kernel(
    const short* __restrict__ Opart, const float* __restrict__ mpart,
    const float* __restrict__ lpart, short* __restrict__ ctxT) {
  const int idx = blockIdx.x * 8 + (threadIdx.x >> 5);  // b*N + n
  const int ct8 = (threadIdx.x & 31) * 8;
  const size_t row = (size_t)idx;
  const size_t sstride = (size_t)B_DIM * N_DIM;

  float mv[SPLIT], lv[SPLIT];
  float mm = -1e30f;
#pragma unroll
  for (int s2 = 0; s2 < SPLIT; ++s2) {
    mv[s2] = mpart[s2 * sstride + row];
    lv[s2] = lpart[s2 * sstride + row];
    mm = fmaxf(mm, mv[s2]);
  }
  float e[SPLIT], L = 0.f;
#pragma unroll
  for (int s2 = 0; s2 < SPLIT; ++s2) {
    e[s2] = __builtin_exp2f(mv[s2] - mm);
    L += e[s2] * lv[s2];
  }
  const float invL = 1.0f / L;

  float acc[8];
#pragma unroll
  for (int j = 0; j < 8; ++j) acc[j] = 0.f;
#pragma unroll
  for (int s2 = 0; s2 < SPLIT; ++s2) {
    bf16x8 ov = *reinterpret_cast<const bf16x8*>(
        &Opart[(s2 * sstride + row) * CT_DIM + ct8]);
#pragma unroll
    for (int j = 0; j < 8; ++j) acc[j] += e[s2] * bf2f(ov[j]);
  }
  struct W4 { u32 a, b, c, d; } wv;
  wv.a = cvtpk(acc[0] * invL, acc[1] * invL);
  wv.b = cvtpk(acc[2] * invL, acc[3] * invL);
  wv.c = cvtpk(acc[4] * invL, acc[5] * invL);
  wv.d = cvtpk(acc[6] * invL, acc[7] * invL);
  *reinterpret_cast<bf16x8*>(&ctxT[row * CT_DIM + ct8]) = __builtin_bit_cast(bf16x8, wv);
}

// Kernel 4: out[b][o][n] = Wo[:, :256] @ ctx + Wo[:, 256:] @ x. Wo is bf16.
// grid = B*(N/32) = 512, block = 256 (2 blocks/CU); wave w owns o [w*64, +64).
__global__ __launch_bounds__(256) void out_kernel(
    const short* __restrict__ wob, const short* __restrict__ ctxT,
    const short* __restrict__ xT, float* __restrict__ out) {
  const int b = blockIdx.x >> 7;
  const int n0 = (blockIdx.x & 127) * 32;
  const int tid = threadIdx.x;
  const int w = tid >> 6;
  const int l = tid & 63;
  const int lr = l & 15;
  const int lg = l >> 4;

  f32x4 zz; zz[0] = 0.f; zz[1] = 0.f; zz[2] = 0.f; zz[3] = 0.f;
  f32x4 acc[4][2];  // [os][ns]
#pragma unroll
  for (int os = 0; os < 4; ++os)
#pragma unroll
    for (int ns = 0; ns < 2; ++ns) acc[os][ns] = zz;

#pragma unroll 4
  for (int kk = 0; kk < 16; ++kk) {
    const short* src = (kk < 8) ? ctxT : xT;
    const int c = (kk & 7) * 32 + lg * 8;
    bf16x8 bf[2], af[4];
#pragma unroll
    for (int ns = 0; ns < 2; ++ns)
      bf[ns] = *reinterpret_cast<const bf16x8*>(&src[((size_t)(b * N_DIM) + n0 + ns * 16 + lr) * 256 + c]);
#pragma unroll
    for (int os = 0; os < 4; ++os)
      af[os] = *reinterpret_cast<const bf16x8*>(
          &wob[(size_t)(w * 64 + os * 16 + lr) * 512 + kk * 32 + lg * 8]);
#pragma unroll
    for (int os = 0; os < 4; ++os)
#pragma unroll
      for (int ns = 0; ns < 2; ++ns) acc[os][ns] = MFMA(af[os], bf[ns], acc[os][ns]);
  }

#pragma unroll
  for (int os = 0; os < 4; ++os)
#pragma unroll
    for (int ns = 0; ns < 2; ++ns)
#pragma unroll
      for (int r = 0; r < 4; ++r) {
        const int oo = w * 64 + os * 16 + lg * 4 + r;
        const int n = n0 + ns * 16 + lr;
        out[((size_t)(b * C_DIM) + oo) * N_DIM + n] = acc[os][ns][r];
      }
}

extern "C" void kernel_launch(void* const* d_in, const int* in_sizes, int n_in,
                              void* d_out, int out_size, void* d_ws, size_t ws_size,
                              hipStream_t stream) {
  const float* x = (const float*)d_in[0];
  const float* Wq = (const float*)d_in[1];
  const float* Wk = (const float*)d_in[2];
  const float* Wv = (const float*)d_in[3];
  const float* Wo = (const float*)d_in[4];
  float* out = (float*)d_out;

  char* ws = (char*)d_ws;
  const size_t SZ_BNCT = (size_t)B_DIM * N_DIM * CT_DIM * sizeof(short);  // 8 MB
  short* qb   = (short*)(ws);
  short* kb   = (short*)(ws + SZ_BNCT);
  short* vtb  = (short*)(ws + 2 * SZ_BNCT);
  short* xT   = (short*)(ws + 3 * SZ_BNCT);
  short* ctxT = (short*)(ws + 4 * SZ_BNCT);
  short* Opart = (short*)(ws + 5 * SZ_BNCT);  // SPLIT * B * N * CT bf16 = 32 MB
  char* p = ws + 5 * SZ_BNCT + (size_t)SPLIT * B_DIM * N_DIM * CT_DIM * sizeof(short);
  float* mpart = (float*)p;                       p += (size_t)SPLIT * B_DIM * N_DIM * 4;
  float* lpart = (float*)p;                       p += (size_t)SPLIT * B_DIM * N_DIM * 4;
  short* wqb = (short*)p;                         p += 65536 * 2;
  short* wkb = (short*)p;                         p += 65536 * 2;
  short* wvb = (short*)p;                         p += 65536 * 2;
  short* wob = (short*)p;

  wconv_kernel<<<320, 256, 0, stream>>>(Wq, Wk, Wv, Wo, wqb, wkb, wvb, wob);
  proj_kernel<<<B_DIM * (N_DIM / 32), 256, 0, stream>>>(x, wqb, wkb, wvb, qb, kb, vtb, xT);
  attn_kernel<<<B_DIM * (N_DIM / 256) * SPLIT, 512, 0, stream>>>(qb, kb, vtb, Opart, mpart, lpart);
  combine_kernel<<<B_DIM * N_DIM / 8, 256, 0, stream>>>(Opart, mpart, lpart, ctxT);
  out_kernel<<<B_DIM * (N_DIM / 32), 256, 0, stream>>>(wob, ctxT, xT, out);
}

// Round 13
// 138.032 us; speedup vs baseline: 1.1049x; 1.1049x over previous
//
#include <hip/hip_runtime.h>

#define B_DIM 4
#define C_DIM 256
#define N_DIM 4096
#define CT_DIM 256
#define SPLIT 4
#define KVBLK 32

typedef float f32x4 __attribute__((ext_vector_type(4)));
typedef float f32x16 __attribute__((ext_vector_type(16)));
typedef short bf16x8 __attribute__((ext_vector_type(8)));
typedef short bf16x4 __attribute__((ext_vector_type(4)));
typedef unsigned int u32;

static __device__ __forceinline__ short f2bf(float f) {
  u32 u = __builtin_bit_cast(u32, f);
  u += 0x7fffu + ((u >> 16) & 1u);
  return (short)(u >> 16);
}
static __device__ __forceinline__ float bf2f(short s) {
  u32 u = ((u32)(unsigned short)s) << 16;
  return __builtin_bit_cast(float, u);
}
// v_cvt_pk_bf16_f32: packs 2 f32 -> 2 bf16 (RNE) in one VALU op.
static __device__ __forceinline__ u32 cvtpk(float lo, float hi) {
  u32 w;
  asm("v_cvt_pk_bf16_f32 %0, %1, %2" : "=v"(w) : "v"(lo), "v"(hi));
  return w;
}

#define MFMA(a, b, c) __builtin_amdgcn_mfma_f32_16x16x32_bf16((a), (b), (c), 0, 0, 0)
#define MFMA32(a, b, c) __builtin_amdgcn_mfma_f32_32x32x16_bf16((a), (b), (c), 0, 0, 0)

static __device__ __forceinline__ void gload16(const void* g, void* l) {
  __builtin_amdgcn_global_load_lds(
      (const __attribute__((address_space(1))) u32*)(g),
      (__attribute__((address_space(3))) u32*)(l), 16, 0, 0);
}

#define LDS_STRIDE 272
// q pre-scale: (1/16) * log2(e) so softmax runs in exp2 basis
#define QSCALE 0.09016844005556021f
// defer-rescale threshold (exp2 basis): P bounded by 2^8
#define THR 8.0f

// Kernel 0: one-shot weight conversion to bf16 (Wq pre-scaled by QSCALE).
__global__ __launch_bounds__(256) void wconv_kernel(
    const float* __restrict__ Wq, const float* __restrict__ Wk,
    const float* __restrict__ Wv, const float* __restrict__ Wo,
    short* __restrict__ wqb, short* __restrict__ wkb,
    short* __restrict__ wvb, short* __restrict__ wob) {
  const int t = blockIdx.x * 256 + threadIdx.x;  // 0..81919
  const float* src;
  short* dst;
  int off;
  float sc = 1.0f;
  if (t < 16384)      { src = Wq; dst = wqb; off = t;         sc = QSCALE; }
  else if (t < 32768) { src = Wk; dst = wkb; off = t - 16384; }
  else if (t < 49152) { src = Wv; dst = wvb; off = t - 32768; }
  else                { src = Wo; dst = wob; off = t - 49152; }
  f32x4 v = *reinterpret_cast<const f32x4*>(src + (size_t)off * 4);
  struct W2 { u32 a, b; } wv2;
  wv2.a = cvtpk(v[0] * sc, v[1] * sc);
  wv2.b = cvtpk(v[2] * sc, v[3] * sc);
  *reinterpret_cast<bf16x4*>(dst + (size_t)off * 4) = __builtin_bit_cast(bf16x4, wv2);
}

// Kernel 1: projections. grid = B * (N/64), block = 256. Weights are bf16.
// qb[b][n][ct] (q pre-scaled via wqb);
// kb[b][n][ct ^ ((n&15)<<3)];
// vtb[b][ct][(n&~31) + ((n&31) ^ (((ct>>1)&3)<<3))];
// xT[b][n][c] plain.
__global__ __launch_bounds__(256) void proj_kernel(
    const float* __restrict__ x, const short* __restrict__ wqb,
    const short* __restrict__ wkb, const short* __restrict__ wvb,
    short* __restrict__ qb, short* __restrict__ kb,
    short* __restrict__ vtb, short* __restrict__ xT) {
  __shared__ short xt[64 * LDS_STRIDE];
  const int b = blockIdx.x >> 6;
  const int n0 = (blockIdx.x & 63) * 64;
  const int tid = threadIdx.x;
  const int w = tid >> 6;
  const int l = tid & 63;
  const int lr = l & 15;
  const int lg = l >> 4;

  // stage x tile (C=256 x 64 n) into LDS transposed as bf16, cvtpk pairs
  {
    const float* xb = x + (size_t)b * C_DIM * N_DIM + n0;
    const int n = tid & 63;
    const int cp = (tid >> 6) * 2;   // 0,2,4,6
#pragma unroll 4
    for (int it = 0; it < 32; ++it) {
      const int c = it * 8 + cp;
      const float v0 = xb[(size_t)c * N_DIM + n];
      const float v1 = xb[(size_t)(c + 1) * N_DIM + n];
      *reinterpret_cast<u32*>(&xt[n * LDS_STRIDE + c]) = cvtpk(v0, v1);
    }
  }
  __syncthreads();

  // write xT to global (coalesced, from LDS)
  {
    const int nn = tid >> 5;
    const int cc = (tid & 31) * 8;
#pragma unroll
    for (int it = 0; it < 8; ++it) {
      const int row = it * 8 + nn;
      bf16x8 v = *reinterpret_cast<const bf16x8*>(&xt[row * LDS_STRIDE + cc]);
      *reinterpret_cast<bf16x8*>(&xT[((size_t)(b * N_DIM) + n0 + row) * C_DIM + cc]) = v;
    }
  }

  f32x4 zz; zz[0] = 0.f; zz[1] = 0.f; zz[2] = 0.f; zz[3] = 0.f;

  // q and k passes: output (n, ct). wave w owns ct range [w*64, w*64+64)
  for (int pass = 0; pass < 2; ++pass) {
    const short* W = pass ? wkb : wqb;
    short* dst = pass ? kb : qb;
    f32x4 acc[4][4];
#pragma unroll
    for (int cs = 0; cs < 4; ++cs)
#pragma unroll
      for (int ns = 0; ns < 4; ++ns) acc[cs][ns] = zz;
#pragma unroll
    for (int kk = 0; kk < 8; ++kk) {
      bf16x8 af[4], bf[4];
#pragma unroll
      for (int ns = 0; ns < 4; ++ns)
        af[ns] = *reinterpret_cast<const bf16x8*>(&xt[(ns * 16 + lr) * LDS_STRIDE + kk * 32 + lg * 8]);
#pragma unroll
      for (int cs = 0; cs < 4; ++cs)
        bf[cs] = *reinterpret_cast<const bf16x8*>(
            &W[(size_t)(w * 64 + cs * 16 + lr) * C_DIM + kk * 32 + lg * 8]);
#pragma unroll
      for (int cs = 0; cs < 4; ++cs)
#pragma unroll
        for (int ns = 0; ns < 4; ++ns) acc[cs][ns] = MFMA(af[ns], bf[cs], acc[cs][ns]);
    }
#pragma unroll
    for (int cs = 0; cs < 4; ++cs)
#pragma unroll
      for (int ns = 0; ns < 4; ++ns)
#pragma unroll
        for (int r = 0; r < 4; ++r) {
          const int n = n0 + ns * 16 + lg * 4 + r;
          const int ct = w * 64 + cs * 16 + lr;
          const int sw = pass ? ((lg * 4 + r) << 3) : 0;  // n&15 == lg*4+r
          dst[((size_t)(b * N_DIM) + n) * CT_DIM + (ct ^ sw)] = f2bf(acc[cs][ns][r]);
        }
  }

  // v pass: output (ct, n), swizzled within 32-wide n groups (f = (ct>>1)&3)
  {
    f32x4 acc[4][4];
#pragma unroll
    for (int as = 0; as < 4; ++as)
#pragma unroll
      for (int ns = 0; ns < 4; ++ns) acc[as][ns] = zz;
#pragma unroll
    for (int kk = 0; kk < 8; ++kk) {
      bf16x8 af[4], bf[4];
#pragma unroll
      for (int as = 0; as < 4; ++as)
        af[as] = *reinterpret_cast<const bf16x8*>(
            &wvb[(size_t)(w * 64 + as * 16 + lr) * C_DIM + kk * 32 + lg * 8]);
#pragma unroll
      for (int ns = 0; ns < 4; ++ns)
        bf[ns] = *reinterpret_cast<const bf16x8*>(&xt[(ns * 16 + lr) * LDS_STRIDE + kk * 32 + lg * 8]);
#pragma unroll
      for (int as = 0; as < 4; ++as)
#pragma unroll
        for (int ns = 0; ns < 4; ++ns) acc[as][ns] = MFMA(af[as], bf[ns], acc[as][ns]);
    }
#pragma unroll
    for (int as = 0; as < 4; ++as)
#pragma unroll
      for (int ns = 0; ns < 4; ++ns)
#pragma unroll
        for (int r = 0; r < 4; ++r) {
          const int ct = w * 64 + as * 16 + lg * 4 + r;
          const int nl = ns * 16 + lr;
          const int nsw = (nl & 32) | ((nl & 31) ^ (((ct >> 1) & 3) << 3));
          vtb[((size_t)(b * CT_DIM) + ct) * N_DIM + n0 + nsw] = f2bf(acc[as][ns][r]);
        }
  }
}

// Kernel 2: flash attention, swapped-QK 32x32x16, O^T accumulation (verified
// structure) + defer-rescale THR=8. grid = 256 (XCD-pinned), block = 512.
__global__ __launch_bounds__(512, 1) void attn_kernel(
    const short* __restrict__ qb, const short* __restrict__ kb,
    const short* __restrict__ vtb, short* __restrict__ Opart,
    float* __restrict__ mpart, float* __restrict__ lpart) {
  __shared__ short klds[3][KVBLK * 256];   // 3 x 16 KB
  __shared__ short vlds[3][256 * KVBLK];   // 3 x 16 KB

  const int bid = blockIdx.x;
  const int xcd = bid & 7;
  const int idx = bid >> 3;          // 0..31
  const int qt = idx & 15;
  const int bs = (idx >> 4) * 8 + xcd;  // 0..15
  const int b = bs >> 2;
  const int s = bs & 3;

  const int tid = threadIdx.x;
  const int w = tid >> 6;            // 0..7
  const int l = tid & 63;
  const int q5 = l & 31;             // this lane's q-row (within wave tile)
  const int h = l >> 5;              // half-wave
  const int nbase = qt * 256 + w * 32;

  const char* kgbase = (const char*)(kb + ((size_t)b * N_DIM) * CT_DIM);
  const char* vgbase = (const char*)(vtb + ((size_t)b * CT_DIM) * N_DIM);
  const int m_begin = s * (N_DIM / SPLIT);
  const int NT = (N_DIM / SPLIT) / KVBLK;  // 32

  // Q as B-operand fragments: lane needs Q[qrow][kk*16 + h*8 + 0..7]
  bf16x8 qf[16];
  {
    const short* qrow = qb + ((size_t)(b * N_DIM) + nbase + q5) * CT_DIM + h * 8;
#pragma unroll
    for (int kk = 0; kk < 16; ++kk)
      qf[kk] = *reinterpret_cast<const bf16x8*>(qrow + kk * 16);
  }

  f32x16 z16;
#pragma unroll
  for (int r = 0; r < 16; ++r) z16[r] = 0.f;
  f32x16 o8[8];  // O^T[ct = g*32 + crow(reg,h)][q = q5]
#pragma unroll
  for (int g = 0; g < 8; ++g) o8[g] = z16;
  float m_r = -1e30f, l_r = 0.f;   // in exp2 basis

  const int ksw = (q5 & 15) << 3;
  const int vswz = ((q5 >> 1) & 3) << 3;

  auto stage = [&](int m0, int buf) {
    const char* ks = kgbase + (size_t)m0 * 512;  // 32 rows x 512B contiguous
#pragma unroll
    for (int i = 0; i < 2; ++i)
      gload16(ks + (w * 2 + i) * 1024 + l * 16,
              (char*)klds[buf] + (w * 2 + i) * 1024);
#pragma unroll
    for (int i = 0; i < 2; ++i) {
      const int base_ct = (w * 2 + i) * 16;
      gload16(vgbase + ((size_t)(base_ct + (l >> 2)) * N_DIM + m0) * 2 + (l & 3) * 16,
              (char*)vlds[buf] + base_ct * 64);
    }
  };

  auto compute = [&](int cur) {
    // ---- S^T = K Q : lane holds S[q5][key = crow(reg,h)] ----
    f32x16 sacc = z16;
    __builtin_amdgcn_s_setprio(1);
#pragma unroll
    for (int kk = 0; kk < 16; ++kk) {
      bf16x8 kf = *reinterpret_cast<const bf16x8*>(
          &klds[cur][q5 * 256 + ((kk * 16 + h * 8) ^ ksw)]);
      sacc = MFMA32(kf, qf[kk], sacc);
    }
    __builtin_amdgcn_s_setprio(0);

    // ---- in-lane softmax (exp2 basis), deferred rescale (THR=8) ----
    float t0 = fmaxf(fmaxf(fmaxf(sacc[0], sacc[1]), fmaxf(sacc[2], sacc[3])),
                     fmaxf(fmaxf(sacc[4], sacc[5]), fmaxf(sacc[6], sacc[7])));
    float t1 = fmaxf(fmaxf(fmaxf(sacc[8], sacc[9]), fmaxf(sacc[10], sacc[11])),
                     fmaxf(fmaxf(sacc[12], sacc[13]), fmaxf(sacc[14], sacc[15])));
    float pmax = fmaxf(t0, t1);
    pmax = fmaxf(pmax, __shfl_xor(pmax, 32));

    const bool need = (bool)__any(pmax - m_r > THR);
    if (need) {
      const float mnew = fmaxf(m_r, pmax);
      const float corr = __builtin_exp2f(m_r - mnew);
      m_r = mnew;
      l_r *= corr;
#pragma unroll
      for (int g = 0; g < 8; ++g)
#pragma unroll
        for (int r = 0; r < 16; ++r) o8[g][r] *= corr;
    }
    float rsum = 0.f;
#pragma unroll
    for (int r = 0; r < 16; ++r) {
      const float p = __builtin_exp2f(sacc[r] - m_r);
      sacc[r] = p;
      rsum += p;
    }
    rsum += __shfl_xor(rsum, 32);
    l_r += rsum;

    // ---- P^T B-operand fragments (cvt_pk + one shfl pair per step) ----
    bf16x8 pb[2];
#pragma unroll
    for (int step = 0; step < 2; ++step) {
      const u32 pA0 = cvtpk(sacc[8 * step + 0], sacc[8 * step + 1]);
      const u32 pA1 = cvtpk(sacc[8 * step + 2], sacc[8 * step + 3]);
      const u32 pB0 = cvtpk(sacc[8 * step + 4], sacc[8 * step + 5]);
      const u32 pB1 = cvtpk(sacc[8 * step + 6], sacc[8 * step + 7]);
      const u32 loc0 = h ? pB0 : pA0;
      const u32 loc1 = h ? pB1 : pA1;
      const u32 rem0 = h ? pA0 : pB0;
      const u32 rem1 = h ? pA1 : pB1;
      const u32 g0 = __shfl_xor(rem0, 32);
      const u32 g1 = __shfl_xor(rem1, 32);
      struct W4 { u32 a, b, c, d; };
      W4 wv;
      wv.a = h ? g0 : loc0;
      wv.b = h ? g1 : loc1;
      wv.c = h ? loc0 : g0;
      wv.d = h ? loc1 : g1;
      pb[step] = __builtin_bit_cast(bf16x8, wv);
    }

    // ---- O^T += V^T P^T ----
    __builtin_amdgcn_s_setprio(1);
#pragma unroll
    for (int step = 0; step < 2; ++step) {
#pragma unroll
      for (int g = 0; g < 8; ++g) {
        const int ct = g * 32 + q5;
        bf16x8 vf = *reinterpret_cast<const bf16x8*>(
            &vlds[cur][ct * KVBLK + ((step * 16 + h * 8) ^ vswz)]);
        o8[g] = MFMA32(vf, pb[step], o8[g]);
      }
    }
    __builtin_amdgcn_s_setprio(0);
  };

  // ---- main loop: 1 barrier per iter, triple buffer, distance-1 prefetch ----
  stage(m_begin, 0);
  int cur = 0;
#pragma unroll 1
  for (int t = 0; t < NT; ++t) {
    if (t + 1 < NT) {
      stage(m_begin + (t + 1) * KVBLK, cur == 2 ? 0 : cur + 1);
      asm volatile("s_waitcnt vmcnt(4)" ::: "memory");
    } else {
      asm volatile("s_waitcnt vmcnt(0)" ::: "memory");
    }
    __builtin_amdgcn_s_barrier();
    __builtin_amdgcn_sched_barrier(0);
    compute(cur);
    cur = (cur == 2) ? 0 : cur + 1;
  }

  // ---- write partials: Opart[s][b][n][ct] bf16, bf16x4 packed per (g,rq) ----
  short* ob = Opart + (size_t)(s * B_DIM + b) * N_DIM * CT_DIM;
  const int n = nbase + q5;
#pragma unroll
  for (int g = 0; g < 8; ++g)
#pragma unroll
    for (int rq = 0; rq < 4; ++rq) {
      struct W2 { u32 a, b; };
      W2 wv;
      wv.a = cvtpk(o8[g][rq * 4 + 0], o8[g][rq * 4 + 1]);
      wv.b = cvtpk(o8[g][rq * 4 + 2], o8[g][rq * 4 + 3]);
      *reinterpret_cast<bf16x4*>(&ob[(size_t)n * CT_DIM + g * 32 + rq * 8 + h * 4]) =
          __builtin_bit_cast(bf16x4, wv);
    }
  if (l < 32) {
    mpart[(size_t)(s * B_DIM + b) * N_DIM + n] = m_r;
    lpart[(size_t)(s * B_DIM + b) * N_DIM + n] = l_r;
  }
}

// Kernel 3: combine SPLIT partials -> ctxT bf16 (B, N, CT).
// grid = B*N/8 blocks x 256; thread = (one n-row) x (8 ct). Vectorized bf16x8.
__global__ __launch_bounds__(256) void combine_kernel(
    const short* __restrict__ Opart, const float* __restrict__ mpart,
    const float* __restrict__ lpart, short* __restrict__ ctxT) {
  const int idx = blockIdx.x * 8 + (threadIdx.x >> 5);  // b*N + n
  const int ct8 = (threadIdx.x & 31) * 8;
  const size_t row = (size_t)idx;
  const size_t sstride = (size_t)B_DIM * N_DIM;

  float mv[SPLIT], lv[SPLIT];
  float mm = -1e30f;
#pragma unroll
  for (int s2 = 0; s2 < SPLIT; ++s2) {
    mv[s2] = mpart[s2 * sstride + row];
    lv[s2] = lpart[s2 * sstride + row];
    mm = fmaxf(mm, mv[s2]);
  }
  float e[SPLIT], L = 0.f;
#pragma unroll
  for (int s2 = 0; s2 < SPLIT; ++s2) {
    e[s2] = __builtin_exp2f(mv[s2] - mm);
    L += e[s2] * lv[s2];
  }
  const float invL = 1.0f / L;

  float acc[8];
#pragma unroll
  for (int j = 0; j < 8; ++j) acc[j] = 0.f;
#pragma unroll
  for (int s2 = 0; s2 < SPLIT; ++s2) {
    bf16x8 ov = *reinterpret_cast<const bf16x8*>(
        &Opart[(s2 * sstride + row) * CT_DIM + ct8]);
#pragma unroll
    for (int j = 0; j < 8; ++j) acc[j] += e[s2] * bf2f(ov[j]);
  }
  struct W4 { u32 a, b, c, d; } wv;
  wv.a = cvtpk(acc[0] * invL, acc[1] * invL);
  wv.b = cvtpk(acc[2] * invL, acc[3] * invL);
  wv.c = cvtpk(acc[4] * invL, acc[5] * invL);
  wv.d = cvtpk(acc[6] * invL, acc[7] * invL);
  *reinterpret_cast<bf16x8*>(&ctxT[row * CT_DIM + ct8]) = __builtin_bit_cast(bf16x8, wv);
}

// Kernel 4: out[b][o][n] = Wo[:, :256] @ ctx + Wo[:, 256:] @ x. Wo is bf16.
// grid = B*(N/64), block = 256.
__global__ __launch_bounds__(256) void out_kernel(
    const short* __restrict__ wob, const short* __restrict__ ctxT,
    const short* __restrict__ xT, float* __restrict__ out) {
  const int b = blockIdx.x >> 6;
  const int n0 = (blockIdx.x & 63) * 64;
  const int tid = threadIdx.x;
  const int w = tid >> 6;
  const int l = tid & 63;
  const int lr = l & 15;
  const int lg = l >> 4;

  f32x4 zz; zz[0] = 0.f; zz[1] = 0.f; zz[2] = 0.f; zz[3] = 0.f;
  f32x4 acc[4][4];  // [os][ns]; wave w owns o range [w*64, w*64+64)
#pragma unroll
  for (int os = 0; os < 4; ++os)
#pragma unroll
    for (int ns = 0; ns < 4; ++ns) acc[os][ns] = zz;

#pragma unroll 4
  for (int kk = 0; kk < 16; ++kk) {
    const short* src = (kk < 8) ? ctxT : xT;
    const int c = (kk & 7) * 32 + lg * 8;
    bf16x8 bf[4], af[4];
#pragma unroll
    for (int ns = 0; ns < 4; ++ns)
      bf[ns] = *reinterpret_cast<const bf16x8*>(&src[((size_t)(b * N_DIM) + n0 + ns * 16 + lr) * 256 + c]);
#pragma unroll
    for (int os = 0; os < 4; ++os)
      af[os] = *reinterpret_cast<const bf16x8*>(
          &wob[(size_t)(w * 64 + os * 16 + lr) * 512 + kk * 32 + lg * 8]);
#pragma unroll
    for (int os = 0; os < 4; ++os)
#pragma unroll
      for (int ns = 0; ns < 4; ++ns) acc[os][ns] = MFMA(af[os], bf[ns], acc[os][ns]);
  }

#pragma unroll
  for (int os = 0; os < 4; ++os)
#pragma unroll
    for (int ns = 0; ns < 4; ++ns)
#pragma unroll
      for (int r = 0; r < 4; ++r) {
        const int oo = w * 64 + os * 16 + lg * 4 + r;
        const int n = n0 + ns * 16 + lr;
        out[((size_t)(b * C_DIM) + oo) * N_DIM + n] = acc[os][ns][r];
      }
}

extern "C" void kernel_launch(void* const* d_in, const int* in_sizes, int n_in,
                              void* d_out, int out_size, void* d_ws, size_t ws_size,
                              hipStream_t stream) {
  const float* x = (const float*)d_in[0];
  const float* Wq = (const float*)d_in[1];
  const float* Wk = (const float*)d_in[2];
  const float* Wv = (const float*)d_in[3];
  const float* Wo = (const float*)d_in[4];
  float* out = (float*)d_out;

  char* ws = (char*)d_ws;
  const size_t SZ_BNCT = (size_t)B_DIM * N_DIM * CT_DIM * sizeof(short);  // 8 MB
  short* qb   = (short*)(ws);
  short* kb   = (short*)(ws + SZ_BNCT);
  short* vtb  = (short*)(ws + 2 * SZ_BNCT);
  short* xT   = (short*)(ws + 3 * SZ_BNCT);
  short* ctxT = (short*)(ws + 4 * SZ_BNCT);
  short* Opart = (short*)(ws + 5 * SZ_BNCT);  // SPLIT * B * N * CT bf16 = 32 MB
  char* p = ws + 5 * SZ_BNCT + (size_t)SPLIT * B_DIM * N_DIM * CT_DIM * sizeof(short);
  float* mpart = (float*)p;                       p += (size_t)SPLIT * B_DIM * N_DIM * 4;
  float* lpart = (float*)p;                       p += (size_t)SPLIT * B_DIM * N_DIM * 4;
  short* wqb = (short*)p;                         p += 65536 * 2;
  short* wkb = (short*)p;                         p += 65536 * 2;
  short* wvb = (short*)p;                         p += 65536 * 2;
  short* wob = (short*)p;

  wconv_kernel<<<320, 256, 0, stream>>>(Wq, Wk, Wv, Wo, wqb, wkb, wvb, wob);
  proj_kernel<<<B_DIM * (N_DIM / 64), 256, 0, stream>>>(x, wqb, wkb, wvb, qb, kb, vtb, xT);
  attn_kernel<<<B_DIM * (N_DIM / 256) * SPLIT, 512, 0, stream>>>(qb, kb, vtb, Opart, mpart, lpart);
  combine_kernel<<<B_DIM * N_DIM / 8, 256, 0, stream>>>(Opart, mpart, lpart, ctxT);
  out_kernel<<<B_DIM * (N_DIM / 64), 256, 0, stream>>>(wob, ctxT, xT, out);
}